// Round 19
// baseline (77.607 us; speedup 1.0000x reference)
//
#include <hip/hip_runtime.h>

// Quantized 3x3 conv, stride 1, pad 1 (pad value = input zero point 3).
// x: int32 [32][128][56][56]; weight: int32 [256][128][3][3]
// bias: int32 [256]; weight_scale: float [256]
// out: int32 [32][256][56][56]

#define NB    32
#define CIN   128
#define HH    56
#define WW    56
#define COUT  256
#define HP    58
#define WP    58
#define PIX   (HH*WW)     // 3136
#define KTOT  1152
#define NCHUNK 18         // K chunks of 64

#define NTP   25          // ceil(3136/128) pixel tiles (tile 24 ragged: 64 px)
#define BNP   128         // pixels per block
#define CHBY  (BNP*64)    // one chunk of B in LDS: 8192 B; RING OF 4
#define PL    (HP*WP*64)  // xp8 plane stride (ci 0-63 / 64-127)
#define BPB   (2*PL)      // 430592 B per batch slab

typedef int v4i __attribute__((ext_vector_type(4)));

#define GLOAD_LDS(gsrc, ldst) \
    __builtin_amdgcn_global_load_lds( \
        (const __attribute__((address_space(1))) void*)(gsrc), \
        (__attribute__((address_space(3))) void*)(ldst), 16, 0, 0)

// ---------------- Phase 1: merged pack (weight + x) -----------------------
// blocks [0,256): weight -> fragment order. blocks [256,..): x -> two-plane
// padded NHWC int8 xp8[nl][q][hp*WP+wp][64], q=ci>>6 (LDS transpose).
__global__ void pack_both_kernel(const int* __restrict__ x,
                                 unsigned char* __restrict__ xp8,
                                 const int* __restrict__ wt,
                                 unsigned char* __restrict__ w8f,
                                 int n0) {
    __shared__ unsigned int lt[WW * 33];
    int bx = blockIdx.x;
    int tid = threadIdx.x;         // 256

    if (bx < COUT) {
        int co = bx;
        for (int idx = tid; idx < KTOT/4; idx += 256) {
            int k  = idx * 4;
            int r  = k >> 7;
            int ci = k & 127;
            const int* wb = wt + ((co*CIN + ci)*9 + r);
            int v0 = wb[0], v1 = wb[9], v2 = wb[18], v3 = wb[27];
            unsigned int pack = (v0 & 0xFF) | ((v1 & 0xFF) << 8) |
                                ((v2 & 0xFF) << 16) | ((unsigned)(v3 & 0xFF) << 24);
            int tch = k >> 6;
            size_t dst = ((size_t)((tch*16 + (co >> 4))*16 + (co & 15)))*64 + (k & 63);
            *(unsigned int*)(w8f + dst) = pack;
        }
        return;
    }

    int bxx = bx - COUT;
    int nl = bxx / HP;
    int hp = bxx % HP;
    int nb = n0 + nl;
    unsigned char* slab = xp8 + (size_t)nl * BPB;
    unsigned int* q0 = (unsigned int*)(slab + (size_t)hp * WP * 64);
    unsigned int* q1 = (unsigned int*)(slab + PL + (size_t)hp * WP * 64);

    if (hp == 0 || hp == HP-1) {
        const v4i zp = {0x03030303, 0x03030303, 0x03030303, 0x03030303};
        v4i* a0 = (v4i*)q0;
        v4i* a1 = (v4i*)q1;
        for (int i = tid; i < (WP*64)/16; i += 256) { a0[i] = zp; a1[i] = zp; }
        return;
    }

    int h  = hp - 1;
    int wl = tid & 63;
    int cg = tid >> 6;
    if (wl < WW) {
        const int s = HH*WW;
#pragma unroll
        for (int k = 0; k < 8; ++k) {
            int ci0 = cg*4 + k*16;
            const int* xb = x + (((size_t)(nb*CIN + ci0)*HH + h)*WW + wl);
            int v0 = xb[0], v1 = xb[s], v2 = xb[2*s], v3 = xb[3*s];
            unsigned int pack = (v0 & 0xFF) | ((v1 & 0xFF) << 8) |
                                ((v2 & 0xFF) << 16) | ((unsigned)(v3 & 0xFF) << 24);
            lt[wl*33 + (ci0 >> 2)] = pack;
        }
    }
    __syncthreads();

#pragma unroll
    for (int it = 0; it < 7; ++it) {
        int idx = it*256 + tid;
        int p = idx >> 5;
        int d = idx & 31;
        unsigned int* qq = (d < 16) ? q0 : q1;
        qq[(p + 1)*16 + (d & 15)] = lt[p*33 + d];
    }
    if (tid < 64) {
        int d = tid & 15;
        unsigned int* qq = (tid & 16) ? q1 : q0;
        int col = (tid & 32) ? (WP-1) : 0;
        qq[col*16 + d] = 0x03030303u;
    }
}

__device__ __forceinline__ int koff_of(int t) {
    int r  = t >> 1;
    int kh = (r >= 6) ? 2 : (r >= 3 ? 1 : 0);
    int kw = r - kh*3;
    return (t & 1) * PL + ((kh*WP + kw) << 6);
}

// ---------------- Phase 2: 4-wave 128x128, M_wave=64 implicit GEMM --------
// Grid: 2 co-halves * 25 px-tiles * nc batches (XCD swizzle). Block: 256
// thr = 4 waves. Wave (pxg=wm>>1, cosub=wm&1) owns 64co x 64px: acc[4][4]
// = 64 AGPR -> ~110 VGPR -> 4 waves/SIMD -> 4 INDEPENDENT blocks/CU.
// Rationale: per-CU LDS b128 reads per chunk drop 112 -> 64 (M_wave 32->64
// halves B re-reads); LDS no longer exceeds the MFMA pipe.
// 2-deep staging, RING-OF-4, one barrier per chunk. 6 VMEM/iter (4 A + 2
// stage). Counted waits (ops younger than own stage(p) pair at barrier(p)):
//   p=0: s(1)x2+a(0)x4+s(2)x2 = 8; mid: a(p-1)x4+s(p+1)x2+a(p)x4+s(p+2)x2
//   = 12; p=16: 10; p=17: 8.
__launch_bounds__(256, 4)
__global__ void conv_kernel(const unsigned char* __restrict__ w8f,
                            const unsigned char* __restrict__ xp8,
                            const int* __restrict__ bias,
                            const float* __restrict__ wscale,
                            int* __restrict__ out,
                            int n0) {
    __shared__ __align__(16) unsigned char ldsB[4*CHBY];

    int nwg = gridDim.x;
    int bx0 = blockIdx.x;
    int q = nwg >> 3, r = nwg & 7;
    int xcd = bx0 & 7, idx8 = bx0 >> 3;
    int bx = (xcd < r ? xcd*(q+1) : r*(q+1) + (xcd-r)*q) + idx8;

    int ch = bx & 1;               // co-half (fastest: pair shares B in L2)
    int rest = bx >> 1;
    int pt = rest % NTP;
    int nl = rest / NTP;
    int nb = n0 + nl;
    int p0 = pt * BNP;

    int tid  = threadIdx.x;
    int lane = tid & 63;
    int wm   = tid >> 6;           // 0..3
    int pxg  = wm >> 1;            // px-group 0/1 (64 px each)
    int cosub = wm & 1;            // co-subgroup 0/1 (64 co each)
    int lr   = lane & 15;
    int lg   = lane >> 4;

    // ---- B staging: wave wm stages slots wm*2, wm*2+1 (16px x 64B) ----
    int l4 = lane >> 2;
    int sw = (lane & 3) ^ ((lane >> 3) & 3);
    int s0u = __builtin_amdgcn_readfirstlane(wm*2);
    int s1u = __builtin_amdgcn_readfirstlane(wm*2+1);
    int pS0 = p0 + (wm*2)*16 + l4;
    int pS1 = p0 + (wm*2+1)*16 + l4;
    if (pS0 >= PIX) pS0 = PIX-1;   // ragged tile 24: clamp (junk, masked)
    if (pS1 >= PIX) pS1 = PIX-1;
    const unsigned char* bsrc0 =
        xp8 + (size_t)nl*BPB + ((size_t)((pS0/WW)*WP + pS0%WW))*64 + sw*16;
    const unsigned char* bsrc1 =
        xp8 + (size_t)nl*BPB + ((size_t)((pS1/WW)*WP + pS1%WW))*64 + sw*16;

    // ---- B fragment read address (swizzled); slot = pxg*4 + j ----
    int rslot = lg ^ ((lr >> 1) & 3);
    int vb = pxg*4096 + lr*64 + rslot*16;            // b[j] at vb + j*1024

    // ---- A fragment base: frag g = ch*8 + cosub*4 + i (i=0..3) ----
    const unsigned char* abase =
        w8f + (size_t)(ch*8 + cosub*4)*1024 + (lr*64 + lg*16);

    v4i acc[4][4];
#pragma unroll
    for (int i = 0; i < 4; ++i)
#pragma unroll
        for (int j = 0; j < 4; ++j)
            acc[i][j] = (v4i){0, 0, 0, 0};

#define STAGE2(T) do {                                                         \
        int k_ = koff_of(T);                                                   \
        GLOAD_LDS(bsrc0 + k_, &ldsB[((T)&3)*CHBY + s0u*1024]);                 \
        GLOAD_LDS(bsrc1 + k_, &ldsB[((T)&3)*CHBY + s1u*1024]);                 \
    } while (0)

    // prologue: stage chunks 0 and 1 (2-deep)
    STAGE2(0);
    STAGE2(1);

#pragma unroll
    for (int p = 0; p < NCHUNK; ++p) {
        // A-loads FIRST (their waits must not drain the fresh stage)
        v4i a_[4];
#pragma unroll
        for (int i = 0; i < 4; ++i)
            a_[i] = *(const v4i*)(abase + (size_t)p*16384 + i*1024);
        __builtin_amdgcn_sched_barrier(0);
        if (p < NCHUNK-2) STAGE2(p+2);

        if (p == 0)             asm volatile("s_waitcnt vmcnt(8)"  ::: "memory");
        else if (p < NCHUNK-2)  asm volatile("s_waitcnt vmcnt(12)" ::: "memory");
        else if (p == NCHUNK-2) asm volatile("s_waitcnt vmcnt(10)" ::: "memory");
        else                    asm volatile("s_waitcnt vmcnt(8)"  ::: "memory");
        __builtin_amdgcn_sched_barrier(0);
        __builtin_amdgcn_s_barrier();      // all waves' chunk-p B in LDS

        int roff = (p & 3) * CHBY;
        v4i b_[4];
#pragma unroll
        for (int j = 0; j < 4; ++j)
            b_[j] = *(const v4i*)&ldsB[roff + vb + j*1024];
        __builtin_amdgcn_s_setprio(1);
#pragma unroll
        for (int i = 0; i < 4; ++i)
#pragma unroll
            for (int j = 0; j < 4; ++j)
                acc[i][j] = __builtin_amdgcn_mfma_i32_16x16x64_i8(
                    a_[i], b_[j], acc[i][j], 0, 0, 0);
        __builtin_amdgcn_s_setprio(0);
        // no trailing barrier: ring-of-4 (slot (p+2)&3 last read at p-2;
        // those reads retired pre-MFMA(p-2), pre-barrier(p-1), pre-issue).
    }
#undef STAGE2

    // Epilogue: q = clamp(rint((acc+bias)*(0.05*ws/0.1) + (-2)), -128, 127)
    int px0 = p0 + pxg*64;
#pragma unroll
    for (int i = 0; i < 4; ++i) {
#pragma unroll
        for (int rr = 0; rr < 4; ++rr) {
            int co = ch*128 + cosub*64 + i*16 + lg*4 + rr;
            float sc = __fdiv_rn(__fmul_rn(0.05f, wscale[co]), 0.1f);
            int bs = bias[co];
            int* orow = out + ((size_t)(nb*COUT + co))*PIX + px0;
#pragma unroll
            for (int j = 0; j < 4; ++j) {
                int px = px0 + j*16 + lr;
                float accf = (float)(acc[i][j][rr] + bs);
                float y = __fadd_rn(__fmul_rn(accf, sc), -2.0f);
                y = rintf(y);
                y = fminf(fmaxf(y, -128.0f), 127.0f);
                if (px < PIX) orow[j*16 + lr] = (int)y;
            }
        }
    }
}

// ---------------- Fallback: naive direct conv (only if ws too small) ------
__launch_bounds__(256)
__global__ void conv_direct_kernel(const int* __restrict__ x,
                                   const int* __restrict__ wt,
                                   const int* __restrict__ bias,
                                   const float* __restrict__ wscale,
                                   int* __restrict__ out) {
    size_t idx = (size_t)blockIdx.x * 256 + threadIdx.x;
    if (idx >= (size_t)NB * COUT * PIX) return;
    int w  = idx % WW;
    int h  = (idx / WW) % HH;
    int co = (idx / PIX) % COUT;
    int nb = idx / ((size_t)PIX * COUT);
    int acc = 0;
    for (int ci = 0; ci < CIN; ++ci) {
        const int* xb = x + ((size_t)(nb*CIN + ci)*HH)*WW;
        const int* wb = wt + ((size_t)(co*CIN + ci)*9);
        for (int kh = 0; kh < 3; ++kh) {
            int hh = h + kh - 1;
            for (int kw = 0; kw < 3; ++kw) {
                int ww2 = w + kw - 1;
                int xv = (hh >= 0 && hh < HH && ww2 >= 0 && ww2 < WW)
                         ? xb[hh*WW + ww2] : 3;
                acc += xv * wb[kh*3 + kw];
            }
        }
    }
    float sc = __fdiv_rn(__fmul_rn(0.05f, wscale[co]), 0.1f);
    float y = __fadd_rn(__fmul_rn((float)(acc + bias[co]), sc), -2.0f);
    y = rintf(y);
    y = fminf(fmaxf(y, -128.0f), 127.0f);
    out[idx] = (int)y;
}

extern "C" void kernel_launch(void* const* d_in, const int* in_sizes, int n_in,
                              void* d_out, int out_size, void* d_ws, size_t ws_size,
                              hipStream_t stream) {
    const int*   x      = (const int*)d_in[0];
    const int*   weight = (const int*)d_in[1];
    const int*   bias   = (const int*)d_in[2];
    const float* wscale = (const float*)d_in[3];
    int*         out    = (int*)d_out;

    const size_t XOFF = 320u << 10;                  // w8f region
    const size_t SLAB = (size_t)COUT * PIX * 4;      // out bytes per batch

    size_t navail = (ws_size > XOFF) ? (ws_size - XOFF) / BPB : 0;

    unsigned char* w8f = (unsigned char*)d_ws;
    unsigned char* xpw = (unsigned char*)d_ws + XOFF;

    if (navail >= 4) {
        int wsN = (int)(navail < 32 ? navail : 32);
        int Na  = 32 - wsN;        // 0..28
        unsigned char* xpt = (unsigned char*)d_out + (size_t)Na * SLAB;

        if (Na > 0) {
            pack_both_kernel<<<dim3(COUT + Na*HP), dim3(256), 0, stream>>>(
                x, xpt, weight, w8f, 0);
            pack_both_kernel<<<dim3(COUT + wsN*HP), dim3(256), 0, stream>>>(
                x, xpw, weight, w8f, Na);
            conv_kernel<<<dim3(2*NTP*Na), dim3(256), 0, stream>>>(
                w8f, xpt, bias, wscale, out, 0);
            conv_kernel<<<dim3(2*NTP*wsN), dim3(256), 0, stream>>>(
                w8f, xpw, bias, wscale, out, Na);
        } else {
            pack_both_kernel<<<dim3(COUT + 32*HP), dim3(256), 0, stream>>>(
                x, xpw, weight, w8f, 0);
            conv_kernel<<<dim3(2*NTP*32), dim3(256), 0, stream>>>(
                w8f, xpw, bias, wscale, out, 0);
        }
    } else if (navail >= 1) {
        int nchk = navail >= 2 ? 2 : 1;
        for (int n0 = 0; n0 < NB; n0 += nchk) {
            int nc = (NB - n0 < nchk) ? (NB - n0) : nchk;
            pack_both_kernel<<<dim3(COUT + nc*HP), dim3(256), 0, stream>>>(
                x, xpw, weight, w8f, n0);
            conv_kernel<<<dim3(2*NTP*nc), dim3(256), 0, stream>>>(
                w8f, xpw, bias, wscale, out, n0);
        }
    } else {
        size_t total = (size_t)NB * COUT * PIX;
        conv_direct_kernel<<<dim3((total + 255) / 256), dim3(256), 0, stream>>>(
            x, weight, bias, wscale, out);
    }
}

// Round 20
// 56.325 us; speedup vs baseline: 1.3778x; 1.3778x over previous
//
#include <hip/hip_runtime.h>

// Quantized 3x3 conv, stride 1, pad 1 (pad value = input zero point 3).
// x: int32 [32][128][56][56]; weight: int32 [256][128][3][3]
// bias: int32 [256]; weight_scale: float [256]
// out: int32 [32][256][56][56]

#define NB    32
#define CIN   128
#define HH    56
#define WW    56
#define COUT  256
#define HP    58
#define WP    58
#define PIX   (HH*WW)     // 3136
#define KTOT  1152
#define NCHUNK 18         // K chunks of 64

#define NPT   28          // pixel tiles per batch (3136 = 28*112)
#define BN    112         // pixels per block
#define NJ    7           // B fragments per wave (112/16)
#define PHB1  (NJ*1024)   // one chunk of B in LDS: 7168 B; RING OF 3
#define PL    (HP*WP*64)  // xp8 plane stride (ci 0-63 / 64-127)
#define BPB   (2*PL)      // 430592 B per batch slab

typedef int v4i __attribute__((ext_vector_type(4)));

#define GLOAD_LDS(gsrc, ldst) \
    __builtin_amdgcn_global_load_lds( \
        (const __attribute__((address_space(1))) void*)(gsrc), \
        (__attribute__((address_space(3))) void*)(ldst), 16, 0, 0)

// ---------------- Phase 1: merged pack (weight + x) -----------------------
// blocks [0,256): weight -> fragment order. blocks [256,..): x -> two-plane
// padded NHWC int8 xp8[nl][q][hp*WP+wp][64], q=ci>>6 (LDS transpose).
__global__ void pack_both_kernel(const int* __restrict__ x,
                                 unsigned char* __restrict__ xp8,
                                 const int* __restrict__ wt,
                                 unsigned char* __restrict__ w8f,
                                 int n0) {
    __shared__ unsigned int lt[WW * 33];
    int bx = blockIdx.x;
    int tid = threadIdx.x;         // 256

    if (bx < COUT) {
        int co = bx;
        for (int idx = tid; idx < KTOT/4; idx += 256) {
            int k  = idx * 4;
            int r  = k >> 7;
            int ci = k & 127;
            const int* wb = wt + ((co*CIN + ci)*9 + r);
            int v0 = wb[0], v1 = wb[9], v2 = wb[18], v3 = wb[27];
            unsigned int pack = (v0 & 0xFF) | ((v1 & 0xFF) << 8) |
                                ((v2 & 0xFF) << 16) | ((unsigned)(v3 & 0xFF) << 24);
            int tch = k >> 6;
            size_t dst = ((size_t)((tch*16 + (co >> 4))*16 + (co & 15)))*64 + (k & 63);
            *(unsigned int*)(w8f + dst) = pack;
        }
        return;
    }

    int bxx = bx - COUT;
    int nl = bxx / HP;
    int hp = bxx % HP;
    int nb = n0 + nl;
    unsigned char* slab = xp8 + (size_t)nl * BPB;
    unsigned int* q0 = (unsigned int*)(slab + (size_t)hp * WP * 64);
    unsigned int* q1 = (unsigned int*)(slab + PL + (size_t)hp * WP * 64);

    if (hp == 0 || hp == HP-1) {
        const v4i zp = {0x03030303, 0x03030303, 0x03030303, 0x03030303};
        v4i* a0 = (v4i*)q0;
        v4i* a1 = (v4i*)q1;
        for (int i = tid; i < (WP*64)/16; i += 256) { a0[i] = zp; a1[i] = zp; }
        return;
    }

    int h  = hp - 1;
    int wl = tid & 63;
    int cg = tid >> 6;
    if (wl < WW) {
        const int s = HH*WW;
#pragma unroll
        for (int k = 0; k < 8; ++k) {
            int ci0 = cg*4 + k*16;
            const int* xb = x + (((size_t)(nb*CIN + ci0)*HH + h)*WW + wl);
            int v0 = xb[0], v1 = xb[s], v2 = xb[2*s], v3 = xb[3*s];
            unsigned int pack = (v0 & 0xFF) | ((v1 & 0xFF) << 8) |
                                ((v2 & 0xFF) << 16) | ((unsigned)(v3 & 0xFF) << 24);
            lt[wl*33 + (ci0 >> 2)] = pack;
        }
    }
    __syncthreads();

#pragma unroll
    for (int it = 0; it < 7; ++it) {
        int idx = it*256 + tid;
        int p = idx >> 5;
        int d = idx & 31;
        unsigned int* qq = (d < 16) ? q0 : q1;
        qq[(p + 1)*16 + (d & 15)] = lt[p*33 + d];
    }
    if (tid < 64) {
        int d = tid & 15;
        unsigned int* qq = (tid & 16) ? q1 : q0;
        int col = (tid & 32) ? (WP-1) : 0;
        qq[col*16 + d] = 0x03030303u;
    }
}

__device__ __forceinline__ int koff_of(int t) {
    int r  = t >> 1;
    int kh = (r >= 6) ? 2 : (r >= 3 ? 1 : 0);
    int kw = r - kh*3;
    return (t & 1) * PL + ((kh*WP + kw) << 6);
}

// ---------------- Phase 2: 8-wave BM=256 with A-REGISTER DOUBLE-BUFFER ----
// Round-15 base (best 58.1us) + the one change: A(p+1) is prefetched into
// alternating registers (aA/aB) BEFORE the barrier, so the per-chunk
// critical path is barrier -> ds_read(~120cy) -> MFMA instead of
// barrier -> L2 A-load(~300cy) -> MFMA (the invariant serializer that kept
// MfmaUtil pinned at ~17% across all schedule variants).
// Queue trace (1-deep B stage, ring-of-3; per-iter issue: a(p+1)x2 then
// stage(p+1)): outstanding at iter-p wait = a(p)x2, stage(p), a(p+1)x2,
// stage(p+1) -> ops younger than stage(p) = 3 -> vmcnt(3) retires stage(p)
// AND a(p) together (p=17: vmcnt(0)). Ring-of-3 WAR with 1-deep stage:
// write (p+1)%3 was last ds_read at iter p-2, two barriers earlier. Safe.
__launch_bounds__(512, 4)
__global__ void conv_kernel(const unsigned char* __restrict__ w8f,
                            const unsigned char* __restrict__ xp8,
                            const int* __restrict__ bias,
                            const float* __restrict__ wscale,
                            int* __restrict__ out,
                            int n0) {
    __shared__ __align__(16) unsigned char ldsB[3*PHB1];

    // Bijective XCD swizzle (m204).
    int nwg = gridDim.x;
    int bx0 = blockIdx.x;
    int q = nwg >> 3, r = nwg & 7;
    int xcd = bx0 & 7, idx8 = bx0 >> 3;
    int bx = (xcd < r ? xcd*(q+1) : r*(q+1) + (xcd-r)*q) + idx8;

    int pt = bx % NPT;
    int nl = bx / NPT;
    int nb = n0 + nl;
    int p0 = pt * BN;

    int tid  = threadIdx.x;
    int lane = tid & 63;
    int wm   = tid >> 6;           // 0..7
    int lr   = lane & 15;
    int lg   = lane >> 4;

    // ---- B staging: wave w stages slot (w<7 ? w : 6), 16px x 64B ----
    int l4 = lane >> 2;
    int sw = (lane & 3) ^ ((lane >> 3) & 3);
    int slot = (wm < 7) ? wm : 6;
    int slotu = __builtin_amdgcn_readfirstlane(slot);
    int pS = p0 + slot*16 + l4;
    int ph = pS / WW, pw = pS % WW;
    const unsigned char* bsrc =
        xp8 + (size_t)nl*BPB + ((size_t)(ph*WP + pw))*64 + sw*16;

    // ---- B fragment read address (swizzled) ----
    int rslot = lg ^ ((lr >> 1) & 3);
    int vb = lr*64 + rslot*16;                       // b[j] at vb + j*1024

    // ---- A fragment base: frag g = wm*2 + i (i=0,1), 1KB each ----
    const unsigned char* abase =
        w8f + (size_t)(wm*2)*1024 + (lr*64 + lg*16);

    v4i acc[2][NJ];
#pragma unroll
    for (int i = 0; i < 2; ++i)
#pragma unroll
        for (int j = 0; j < NJ; ++j)
            acc[i][j] = (v4i){0, 0, 0, 0};

#define STAGE1(T) \
    GLOAD_LDS(bsrc + koff_of(T), &ldsB[((T)%3)*PHB1 + slotu*1024])

    v4i aA[2], aB[2];
    // prologue: A(0) loads FIRST, then stage chunk 0 (so the compiler's
    // wait for aA at MFMA(0) is already satisfied by the iter-0 vmcnt).
#pragma unroll
    for (int i = 0; i < 2; ++i) aA[i] = *(const v4i*)(abase + i*1024);
    STAGE1(0);

#define ITER(P, AC, ANX) do {                                                  \
        if ((P) < NCHUNK-1) {                                                  \
            _Pragma("unroll")                                                  \
            for (int i_ = 0; i_ < 2; ++i_)                                     \
                ANX[i_] = *(const v4i*)(abase + (size_t)((P)+1)*16384          \
                                        + i_*1024);                            \
            __builtin_amdgcn_sched_barrier(0);                                 \
            STAGE1((P)+1);                                                     \
            asm volatile("s_waitcnt vmcnt(3)" ::: "memory");                   \
        } else {                                                               \
            asm volatile("s_waitcnt vmcnt(0)" ::: "memory");                   \
        }                                                                      \
        __builtin_amdgcn_sched_barrier(0);                                     \
        __builtin_amdgcn_s_barrier();      /* chunk-P B visible in LDS */      \
        {                                                                      \
            int roff_ = ((P) % 3) * PHB1;                                      \
            v4i b_[NJ];                                                        \
            _Pragma("unroll")                                                  \
            for (int j_ = 0; j_ < NJ; ++j_)                                    \
                b_[j_] = *(const v4i*)&ldsB[roff_ + vb + j_*1024];             \
            __builtin_amdgcn_s_setprio(1);                                     \
            _Pragma("unroll")                                                  \
            for (int i_ = 0; i_ < 2; ++i_)                                     \
                _Pragma("unroll")                                              \
                for (int j_ = 0; j_ < NJ; ++j_)                                \
                    acc[i_][j_] = __builtin_amdgcn_mfma_i32_16x16x64_i8(       \
                        AC[i_], b_[j_], acc[i_][j_], 0, 0, 0);                 \
            __builtin_amdgcn_s_setprio(0);                                     \
        }                                                                      \
    } while (0)

#pragma unroll
    for (int tt = 0; tt < NCHUNK/2; ++tt) {
        ITER(2*tt,   aA, aB);
        ITER(2*tt+1, aB, aA);
    }
#undef ITER
#undef STAGE1

    // Epilogue: q = clamp(rint((acc+bias)*(0.05*ws/0.1) + (-2)), -128, 127)
#pragma unroll
    for (int i = 0; i < 2; ++i) {
#pragma unroll
        for (int rr = 0; rr < 4; ++rr) {
            int co = wm*32 + i*16 + lg*4 + rr;
            float sc = __fdiv_rn(__fmul_rn(0.05f, wscale[co]), 0.1f);
            int bs = bias[co];
            int* orow = out + ((size_t)(nb*COUT + co))*PIX + p0;
#pragma unroll
            for (int j = 0; j < NJ; ++j) {
                float accf = (float)(acc[i][j][rr] + bs);
                float y = __fadd_rn(__fmul_rn(accf, sc), -2.0f);
                y = rintf(y);
                y = fminf(fmaxf(y, -128.0f), 127.0f);
                orow[j*16 + lr] = (int)y;
            }
        }
    }
}

// ---------------- Fallback: naive direct conv (only if ws too small) ------
__launch_bounds__(256)
__global__ void conv_direct_kernel(const int* __restrict__ x,
                                   const int* __restrict__ wt,
                                   const int* __restrict__ bias,
                                   const float* __restrict__ wscale,
                                   int* __restrict__ out) {
    size_t idx = (size_t)blockIdx.x * 256 + threadIdx.x;
    if (idx >= (size_t)NB * COUT * PIX) return;
    int w  = idx % WW;
    int h  = (idx / WW) % HH;
    int co = (idx / PIX) % COUT;
    int nb = idx / ((size_t)PIX * COUT);
    int acc = 0;
    for (int ci = 0; ci < CIN; ++ci) {
        const int* xb = x + ((size_t)(nb*CIN + ci)*HH)*WW;
        const int* wb = wt + ((size_t)(co*CIN + ci)*9);
        for (int kh = 0; kh < 3; ++kh) {
            int hh = h + kh - 1;
            for (int kw = 0; kw < 3; ++kw) {
                int ww2 = w + kw - 1;
                int xv = (hh >= 0 && hh < HH && ww2 >= 0 && ww2 < WW)
                         ? xb[hh*WW + ww2] : 3;
                acc += xv * wb[kh*3 + kw];
            }
        }
    }
    float sc = __fdiv_rn(__fmul_rn(0.05f, wscale[co]), 0.1f);
    float y = __fadd_rn(__fmul_rn((float)(acc + bias[co]), sc), -2.0f);
    y = rintf(y);
    y = fminf(fmaxf(y, -128.0f), 127.0f);
    out[idx] = (int)y;
}

extern "C" void kernel_launch(void* const* d_in, const int* in_sizes, int n_in,
                              void* d_out, int out_size, void* d_ws, size_t ws_size,
                              hipStream_t stream) {
    const int*   x      = (const int*)d_in[0];
    const int*   weight = (const int*)d_in[1];
    const int*   bias   = (const int*)d_in[2];
    const float* wscale = (const float*)d_in[3];
    int*         out    = (int*)d_out;

    const size_t XOFF = 320u << 10;                  // w8f region
    const size_t SLAB = (size_t)COUT * PIX * 4;      // out bytes per batch

    size_t navail = (ws_size > XOFF) ? (ws_size - XOFF) / BPB : 0;

    unsigned char* w8f = (unsigned char*)d_ws;
    unsigned char* xpw = (unsigned char*)d_ws + XOFF;

    if (navail >= 4) {
        int wsN = (int)(navail < 32 ? navail : 32);
        int Na  = 32 - wsN;        // 0..28
        unsigned char* xpt = (unsigned char*)d_out + (size_t)Na * SLAB;

        if (Na > 0) {
            pack_both_kernel<<<dim3(COUT + Na*HP), dim3(256), 0, stream>>>(
                x, xpt, weight, w8f, 0);
            pack_both_kernel<<<dim3(COUT + wsN*HP), dim3(256), 0, stream>>>(
                x, xpw, weight, w8f, Na);
            conv_kernel<<<dim3(NPT*Na), dim3(512), 0, stream>>>(
                w8f, xpt, bias, wscale, out, 0);
            conv_kernel<<<dim3(NPT*wsN), dim3(512), 0, stream>>>(
                w8f, xpw, bias, wscale, out, Na);
        } else {
            pack_both_kernel<<<dim3(COUT + 32*HP), dim3(256), 0, stream>>>(
                x, xpw, weight, w8f, 0);
            conv_kernel<<<dim3(NPT*32), dim3(512), 0, stream>>>(
                w8f, xpw, bias, wscale, out, 0);
        }
    } else if (navail >= 1) {
        int nchk = navail >= 2 ? 2 : 1;
        for (int n0 = 0; n0 < NB; n0 += nchk) {
            int nc = (NB - n0 < nchk) ? (NB - n0) : nchk;
            pack_both_kernel<<<dim3(COUT + nc*HP), dim3(256), 0, stream>>>(
                x, xpw, weight, w8f, n0);
            conv_kernel<<<dim3(NPT*nc), dim3(512), 0, stream>>>(
                w8f, xpw, bias, wscale, out, n0);
        }
    } else {
        size_t total = (size_t)NB * COUT * PIX;
        conv_direct_kernel<<<dim3((total + 255) / 256), dim3(256), 0, stream>>>(
            x, weight, bias, wscale, out);
    }
}